// Round 4
// baseline (203.496 us; speedup 1.0000x reference)
//
#include <hip/hip_runtime.h>
#include <math.h>

namespace {

constexpr int CIN  = 64;
constexpr int COUT = 128;
constexpr int LEN  = 4096;
constexpr int NT   = 256;
constexpr float INV_SQRT2 = 0.70710678118654752440f;

// Fast exact-enough GELU (tanh form as t*e/(e+1)). End-to-end absmax 0.0156
// vs 0.0753 threshold measured in R2/R3.
__device__ __forceinline__ float gelu_fast(float t) {
    float t3 = t * t * t;
    float y  = 1.5957691216057308f * fmaf(0.044715f, t3, t);
    float e  = __expf(y);
    float d  = __builtin_amdgcn_rcpf(e + 1.0f);
    return t - t * d;   // t*e/(e+1); correct limits at +/-inf
}

// Compute 4 h-pairs (conv7+bn+gelu+leaky) -> 4 Haar (L,H) coefficients.
// E[j] = xe[q-2+j], O[j] = xo[q-2+j] for quad of pairs q..q+3.
__device__ __forceinline__ void quadAB(const float* __restrict__ E,
                                       const float* __restrict__ O,
                                       const float* __restrict__ wc,
                                       float inv, float shift,
                                       float4& Lv, float4& Hv) {
    float Lw[4], Hw[4];
    #pragma unroll
    for (int s = 0; s < 4; ++s) {
        // h[2t]: x[2t-3..2t+3] -> xo[t-2],xe[t-1],xo[t-1],xe[t],xo[t],xe[t+1],xo[t+1]
        float he = O[s] * wc[0];
        he = fmaf(E[1 + s], wc[1], he);
        he = fmaf(O[s + 1], wc[2], he);
        he = fmaf(E[2 + s], wc[3], he);
        he = fmaf(O[s + 2], wc[4], he);
        he = fmaf(E[3 + s], wc[5], he);
        he = fmaf(O[s + 3], wc[6], he);
        // h[2t+1]: x[2t-2..2t+4]
        float ho = E[1 + s] * wc[0];
        ho = fmaf(O[s + 1], wc[1], ho);
        ho = fmaf(E[2 + s], wc[2], ho);
        ho = fmaf(O[s + 2], wc[3], ho);
        ho = fmaf(E[3 + s], wc[4], ho);
        ho = fmaf(O[s + 3], wc[5], ho);
        ho = fmaf(E[4 + s], wc[6], ho);

        const float te = fmaf(he, inv, shift);
        const float to = fmaf(ho, inv, shift);
        float ge = gelu_fast(te);
        float go = gelu_fast(to);
        ge = fmaxf(ge, 0.01f * ge);
        go = fmaxf(go, 0.01f * go);
        Lw[s] = (ge + go) * INV_SQRT2;
        Hw[s] = (ge - go) * INV_SQRT2;
    }
    Lv = make_float4(Lw[0], Lw[1], Lw[2], Lw[3]);
    Hv = make_float4(Hw[0], Hw[1], Hw[2], Hw[3]);
}

// One block = (n, oc, half-row). 256 threads, x4 coarsening (1024 pairs/half).
// LDS layouts (pair index t; tb = half*1024):
//   sxe[p] = xe[tb-6+p] = x[2*(tb-6+p)],  p in [0,1036)  (zeros outside row)
//   sxo[p] = xo[tb-6+p] = x[2*(tb-6+p)+1]
//   sL[p]  = xL0[tb-4+p], sH[p] = xH0[tb-4+p], p in [0,1032)
// Main quad of thread tid: q = tb+4*tid -> sL/sH float4 index tid+1.
// Halo quads (threads 0,1): q = tb-4 -> idx 0; q = tb+1024 -> idx 257;
// zeroed when outside [0,2048) (conv2 zero-pads xL0/xH0).
__global__ __launch_bounds__(NT, 8) void fused_wavelet_kernel(
    const float* __restrict__ x,
    const float* __restrict__ w1,
    const float* __restrict__ g1,
    const float* __restrict__ b1,
    const float* __restrict__ m1,
    const float* __restrict__ v1,
    const float* __restrict__ w2L,
    const float* __restrict__ w2H,
    const float* __restrict__ wskip,
    float* __restrict__ out)
{
    __shared__ float sxe[1040];
    __shared__ float sxo[1040];
    __shared__ float sL[1040];
    __shared__ float sH[1040];
    // 4*1040*4 = 16640 B -> LDS allows 9 blocks/CU; VGPR<=64 -> 8 blocks.

    const int tid  = threadIdx.x;
    const unsigned bid = blockIdx.x;
    const int half = bid & 1;
    const int oc   = (bid >> 1) & (COUT - 1);
    const int n    = bid >> 8;            // /(COUT*2)
    const int ic   = oc >> 1;
    const int tb   = half << 10;          // pair-index base

    // --- Stage x: coalesced float4 load + deinterleave (518 float4s) ---
    const float4* xrow4 = (const float4*)(x + (size_t)(n * CIN + ic) * LEN);
    const int fb = half ? 509 : -3;       // (tb-6)/2
    auto stage = [&](int m) {
        const int f = fb + m;
        float4 v = make_float4(0.f, 0.f, 0.f, 0.f);
        if (f >= 0 && f < LEN / 4) v = xrow4[f];
        *(float2*)(sxe + 2 * m) = make_float2(v.x, v.z);
        *(float2*)(sxo + 2 * m) = make_float2(v.y, v.w);
    };
    stage(tid);
    stage(tid + 256);
    if (tid < 6) stage(tid + 512);

    // Uniform channel constants (scalar loads).
    float wc[7];
    #pragma unroll
    for (int k = 0; k < 7; ++k) wc[k] = w1[oc * 7 + k];
    const float inv   = g1[oc] * rsqrtf(v1[oc] + 1e-5f);
    const float shift = b1[oc] - m1[oc] * inv;

    __syncthreads();

    // --- Stage A+B: main quad (keep E/O for the skip path) ---
    const float4* sxe4 = (const float4*)sxe;
    const float4* sxo4 = (const float4*)sxo;
    float E[8], O[8];
    {
        const float4 e0 = sxe4[tid + 1], e1 = sxe4[tid + 2];
        const float4 o0 = sxo4[tid + 1], o1 = sxo4[tid + 2];
        E[0]=e0.x; E[1]=e0.y; E[2]=e0.z; E[3]=e0.w;
        E[4]=e1.x; E[5]=e1.y; E[6]=e1.z; E[7]=e1.w;
        O[0]=o0.x; O[1]=o0.y; O[2]=o0.z; O[3]=o0.w;
        O[4]=o1.x; O[5]=o1.y; O[6]=o1.z; O[7]=o1.w;
    }
    {
        float4 Lv, Hv;
        quadAB(E, O, wc, inv, shift, Lv, Hv);
        ((float4*)sL)[tid + 1] = Lv;
        ((float4*)sH)[tid + 1] = Hv;
    }
    // Halo quads.
    if (tid < 2) {
        const int i4 = tid ? 257 : 0;
        const int q  = tid ? (tb + 1024) : (tb - 4);
        float4 Lv = make_float4(0.f, 0.f, 0.f, 0.f);
        float4 Hv = Lv;
        if (q >= 0 && q + 3 < 2048) {
            float e[8], o[8];
            const float4 e0 = sxe4[i4], e1 = sxe4[i4 + 1];
            const float4 o0 = sxo4[i4], o1 = sxo4[i4 + 1];
            e[0]=e0.x; e[1]=e0.y; e[2]=e0.z; e[3]=e0.w;
            e[4]=e1.x; e[5]=e1.y; e[6]=e1.z; e[7]=e1.w;
            o[0]=o0.x; o[1]=o0.y; o[2]=o0.z; o[3]=o0.w;
            o[4]=o1.x; o[5]=o1.y; o[6]=o1.z; o[7]=o1.w;
            quadAB(e, o, wc, inv, shift, Lv, Hv);
        }
        ((float4*)sL)[i4] = Lv;
        ((float4*)sH)[i4] = Hv;
    }
    __syncthreads();

    // --- Stage C: conv7(xL0)+conv3(xH0) -> inverse Haar + skip + leaky ---
    float wl[7], wh[3];
    #pragma unroll
    for (int k = 0; k < 7; ++k) wl[k] = w2L[oc * 7 + k];
    #pragma unroll
    for (int k = 0; k < 3; ++k) wh[k] = w2H[oc * 3 + k];
    const float ws = wskip[oc];

    float Lb[12], Hb[12];
    {
        const float4* sL4 = (const float4*)sL;
        const float4* sH4 = (const float4*)sH;
        const float4 p0 = sL4[tid], p1 = sL4[tid + 1], p2 = sL4[tid + 2];
        const float4 q0 = sH4[tid], q1 = sH4[tid + 1], q2 = sH4[tid + 2];
        Lb[0]=p0.x; Lb[1]=p0.y; Lb[2]=p0.z; Lb[3]=p0.w;
        Lb[4]=p1.x; Lb[5]=p1.y; Lb[6]=p1.z; Lb[7]=p1.w;
        Lb[8]=p2.x; Lb[9]=p2.y; Lb[10]=p2.z; Lb[11]=p2.w;
        Hb[0]=q0.x; Hb[1]=q0.y; Hb[2]=q0.z; Hb[3]=q0.w;
        Hb[4]=q1.x; Hb[5]=q1.y; Hb[6]=q1.z; Hb[7]=q1.w;
        Hb[8]=q2.x; Hb[9]=q2.y; Hb[10]=q2.z; Hb[11]=q2.w;
    }
    // Lb[i] = xL0[q-4+i], Hb[i] = xH0[q-4+i]  (q = tb+4*tid)

    float res[8];
    #pragma unroll
    for (int s = 0; s < 4; ++s) {
        float xl = Lb[1 + s] * wl[0];
        xl = fmaf(Lb[2 + s], wl[1], xl);
        xl = fmaf(Lb[3 + s], wl[2], xl);
        xl = fmaf(Lb[4 + s], wl[3], xl);
        xl = fmaf(Lb[5 + s], wl[4], xl);
        xl = fmaf(Lb[6 + s], wl[5], xl);
        xl = fmaf(Lb[7 + s], wl[6], xl);
        float xh = Hb[3 + s] * wh[0];
        xh = fmaf(Hb[4 + s], wh[1], xh);
        xh = fmaf(Hb[5 + s], wh[2], xh);

        const float re = (xl + xh) * INV_SQRT2;
        const float ro = (xl - xh) * INV_SQRT2;

        // skip: x[2t] = xe[t] = E[2+s], x[2t+1] = xo[t] = O[2+s]
        float oe = fmaf(E[2 + s], ws, re);
        float oo = fmaf(O[2 + s], ws, ro);
        oe = fmaxf(oe, 0.01f * oe);
        oo = fmaxf(oo, 0.01f * oo);
        res[2 * s]     = oe;
        res[2 * s + 1] = oo;
    }

    float4* orow4 = (float4*)(out + (size_t)(n * COUT + oc) * LEN);
    const int ob = (half << 9) + 2 * tid;   // half*512 + 2*tid
    orow4[ob]     = make_float4(res[0], res[1], res[2], res[3]);
    orow4[ob + 1] = make_float4(res[4], res[5], res[6], res[7]);
}

} // namespace

extern "C" void kernel_launch(void* const* d_in, const int* in_sizes, int n_in,
                              void* d_out, int out_size, void* d_ws, size_t ws_size,
                              hipStream_t stream) {
    const float* x    = (const float*)d_in[0];
    const float* w1   = (const float*)d_in[1];
    const float* g1   = (const float*)d_in[2];
    const float* b1   = (const float*)d_in[3];
    const float* m1   = (const float*)d_in[4];
    const float* v1   = (const float*)d_in[5];
    const float* w2L  = (const float*)d_in[6];
    const float* w2H  = (const float*)d_in[7];
    const float* wsk  = (const float*)d_in[8];
    float* out = (float*)d_out;

    const int Bn = in_sizes[0] / (CIN * LEN);   // batch = 64
    fused_wavelet_kernel<<<dim3(Bn * COUT * 2), dim3(NT), 0, stream>>>(
        x, w1, g1, b1, m1, v1, w2L, w2H, wsk, out);
}